// Round 1
// baseline (141.000 us; speedup 1.0000x reference)
//
#include <hip/hip_runtime.h>
#include <math.h>

#define NP   512
#define NT   1024
#define NS   25
#define NPS  (NP*NS)            // 12800
#define MASKN (NP*NT*NS)        // 13107200

// ws layout (in doubles):
//  [0,NPS)        dsx
//  [NPS,2NPS)     dsy
//  [2NPS,3NPS)    dsz
//  [3NPS, +3*NP)  pd  (AoS [NP][3])
//  TB = 3*NPS+3*NP: 14 SoA arrays of NT doubles:
//     0:nx 1:ny 2:nz 3:kk 4:a0 5:a1 6:a2 7:b0 8:c0 9:B 10:D 11:E 12:F 13:G2
//  emptyMask: 512 uint32 at byte offset (TB+14*NT)*8
#define TB        (3*NPS + 3*NP)
#define EMPTY_OFF ((size_t)(TB + 14*NT) * 8)

__global__ void prep_points(const float* __restrict__ p,
                            const float* __restrict__ l,
                            const float* __restrict__ hemi,
                            double* __restrict__ ws) {
    int idx = blockIdx.x * 256 + threadIdx.x;
    if (idx >= NPS) return;
    int pi = idx / NS, si = idx % NS;
    double px = p[pi*3+0], py = p[pi*3+1], pz = p[pi*3+2];
    double lx = l[0], ly = l[1], lz = l[2];
    double ux = lx - px, uy = ly - py, uz = lz - pz;
    double nrm = sqrt(ux*ux + uy*uy + uz*uz);
    ux /= nrm; uy /= nrm; uz /= nrm;
    double c = -uy;                    // dot((0,-1,0), u_hat)
    // w = cross((0,-1,0), u_hat) = (-uz, 0, ux)
    double wx = -uz, wy = 0.0, wz = ux;
    // M = skew(w)
    double m00 = 0.0, m01 = -wz, m02 =  wy;
    double m10 =  wz, m11 = 0.0, m12 = -wx;
    double m20 = -wy, m21 =  wx, m22 = 0.0;
    // Q = M*M
    double q00 = m00*m00 + m01*m10 + m02*m20;
    double q01 = m00*m01 + m01*m11 + m02*m21;
    double q02 = m00*m02 + m01*m12 + m02*m22;
    double q10 = m10*m00 + m11*m10 + m12*m20;
    double q11 = m10*m01 + m11*m11 + m12*m21;
    double q12 = m10*m02 + m11*m12 + m12*m22;
    double q20 = m20*m00 + m21*m10 + m22*m20;
    double q21 = m20*m01 + m21*m11 + m22*m21;
    double q22 = m20*m02 + m21*m12 + m22*m22;
    double ic = 1.0 + c;
    double r00 = 1.0 + m00 + q00/ic, r01 = m01 + q01/ic, r02 = m02 + q02/ic;
    double r10 = m10 + q10/ic, r11 = 1.0 + m11 + q11/ic, r12 = m12 + q12/ic;
    double r20 = m20 + q20/ic, r21 = m21 + q21/ic, r22 = 1.0 + m22 + q22/ic;
    double hx = hemi[si*3+0], hy = hemi[si*3+1], hz = hemi[si*3+2];
    double lhx = r00*hx + r01*hy + r02*hz + lx;
    double lhy = r10*hx + r11*hy + r12*hz + ly;
    double lhz = r20*hx + r21*hy + r22*hz + lz;
    ws[idx]         = lhx - px;   // dsx
    ws[NPS + idx]   = lhy - py;   // dsy
    ws[2*NPS + idx] = lhz - pz;   // dsz
}

__global__ void prep_tris(const float* __restrict__ V,
                          double* __restrict__ ws,
                          unsigned* __restrict__ emptyMask) {
    int n = blockIdx.x * 256 + threadIdx.x;
    if (n < NP) emptyMask[n] = 0u;
    if (n >= NT) return;
    const float* v = V + n*12;
    double v0x=v[0], v0y=v[1], v0z=v[2];
    double v1x=v[3], v1y=v[4], v1z=v[5];
    double v2x=v[6], v2y=v[7], v2z=v[8];
    double v3x=v[9], v3y=v[10], v3z=v[11];
    double e1x=v1x-v0x, e1y=v1y-v0y, e1z=v1z-v0z;
    double e2x=v2x-v0x, e2y=v2y-v0y, e2z=v2z-v0z;
    double cx = e1y*e2z - e1z*e2y;
    double cy = e1z*e2x - e1x*e2z;
    double cz = e1x*e2y - e1y*e2x;
    double nn = sqrt(cx*cx + cy*cy + cz*cz);
    double nx = cx/nn, ny = cy/nn, nz = cz/nn;
    double kk = -(nx*v3x + ny*v3y + nz*v3z);
    double a0=v0x, a1=v0y, a2=v0z;
    double b0=v1x, b1=v1y, b2=v1z;
    double c0=v2x, c1=v2y, c2=v2z;
    double Bc = a0*b2 - a2*b0;
    double Dc = a0*b1 - a1*b0;
    double Ec = a0*c2 - a2*c0;
    double G2 = a1*c0 - a0*c1;
    double Fc = Bc*G2;
    double* T = ws + TB;
    T[0*NT+n]=nx;  T[1*NT+n]=ny;  T[2*NT+n]=nz;  T[3*NT+n]=kk;
    T[4*NT+n]=a0;  T[5*NT+n]=a1;  T[6*NT+n]=a2;  T[7*NT+n]=b0;
    T[8*NT+n]=c0;  T[9*NT+n]=Bc;  T[10*NT+n]=Dc; T[11*NT+n]=Ec;
    T[12*NT+n]=Fc; T[13*NT+n]=G2;
}

__global__ void prep_scatter(const int* __restrict__ indices,
                             const int* __restrict__ pointindex,
                             const float* __restrict__ COL,
                             const float* __restrict__ OPA,
                             const float* __restrict__ p,
                             const float* __restrict__ l,
                             unsigned* __restrict__ emptyMask,
                             float* __restrict__ out,
                             double* __restrict__ ws) {
    int i = blockIdx.x * 256 + threadIdx.x;
    if (i >= NP) return;
    int pidx = pointindex[i];
    int local = pidx & (NP - 1);          // pidx % 512 (pidx >= 0)
    int surf = indices[pidx*2 + 0];       // in [0,8)
    int mat  = indices[pidx*2 + 1];
    atomicOr(&emptyMask[local], 1u << surf);
    float* colOut = out + MASKN;
    float* opaOut = out + MASKN + 3*NP;
    float* refOut = out + MASKN + 4*NP;
    colOut[i*3+0] = COL[(surf*8+mat)*3+0];
    colOut[i*3+1] = COL[(surf*8+mat)*3+1];
    colOut[i*3+2] = COL[(surf*8+mat)*3+2];
    float o = OPA[surf*8+mat];
    opaOut[i] = fminf(fmaxf(o, 0.0f), 1.0f);
    refOut[i*3+0] = (float)((double)l[0] - (double)p[i*3+0]);
    refOut[i*3+1] = (float)((double)l[1] - (double)p[i*3+1]);
    refOut[i*3+2] = (float)((double)l[2] - (double)p[i*3+2]);
    double* pd = ws + 3*NPS;
    pd[i*3+0] = (double)p[i*3+0];
    pd[i*3+1] = (double)p[i*3+1];
    pd[i*3+2] = (double)p[i*3+2];
}

__global__ __launch_bounds__(256) void diffuse_main(
        const double* __restrict__ ws,
        const unsigned* __restrict__ emptyMask,
        float* __restrict__ out) {
    unsigned f = blockIdx.x * 256u + threadIdx.x;   // grid exactly MASKN/256
    unsigned n  = f & 1023u;        // triangle for t (scrambled)
    unsigned ps = f >> 10;          // ray row for t (block-uniform)
    unsigned pi = ps / 25u;
    const double* dsx = ws;
    const double* dsy = ws + NPS;
    const double* dsz = ws + 2*NPS;
    const double* pd  = ws + 3*NPS;
    const double* T   = ws + TB;
    const double* nx = T;          const double* ny = T + NT;
    const double* nz = T + 2*NT;   const double* kk = T + 3*NT;
    const double* a0 = T + 4*NT;   const double* a1 = T + 5*NT;
    const double* a2 = T + 6*NT;   const double* b0 = T + 7*NT;
    const double* c0 = T + 8*NT;   const double* Bc = T + 9*NT;
    const double* Dc = T + 10*NT;  const double* Ec = T + 11*NT;
    const double* Fc = T + 12*NT;  const double* G2 = T + 13*NT;

    double nxv = nx[n], nyv = ny[n], nzv = nz[n];
    double px = pd[pi*3+0], py = pd[pi*3+1], pz = pd[pi*3+2];
    double vo = px*nxv + py*nyv + pz*nzv;
    double vd = dsx[ps]*nxv + dsy[ps]*nyv + dsz[ps]*nzv;
    double t = -(kk[n] + vo) / vd;

    // unscrambled output coordinates
    unsigned pp  = f / 25600u;
    unsigned rem = f - pp * 25600u;
    unsigned nn  = rem / 25u;
    unsigned ss  = rem - nn * 25u;
    bool empty = (nn < 8u) && ((emptyMask[pp] >> nn) & 1u);
    bool viable = (t > -1e-4) && (t < 1.0) && !empty;

    unsigned ps2 = pp * 25u + ss;
    double ox = pd[pp*3+0], oy = pd[pp*3+1], oz = pd[pp*3+2];
    double r0 = ox + t * dsx[ps2];
    double r1 = oy + t * dsy[ps2];
    double r2 = oz + t * dsz[ps2];

    double a0v = a0[nn], a1v = a1[nn], a2v = a2[nn];
    double Dv = Dc[nn], Bv = Bc[nn], Ev = Ec[nn], Fv = Fc[nn], Gv = G2[nn];
    double A = a0v*r2 - a2v*r0;
    double C = a0v*r1 - a1v*r0;
    double gam  = (Dv*(A*Dv - Bv*C)) / (Dv*(Ev*Dv + Fv));
    double beta = (C + gam*Gv) / Dv;
    double alpha = (r0 - (beta*b0[nn] + gam*c0[nn])) / a0v;

    out[f] = (viable && beta > 0.0 && gam > 0.0 && alpha > 0.0) ? 1.0f : 0.0f;
}

extern "C" void kernel_launch(void* const* d_in, const int* in_sizes, int n_in,
                              void* d_out, int out_size, void* d_ws, size_t ws_size,
                              hipStream_t stream) {
    const float* V         = (const float*)d_in[0];
    const int*   indices   = (const int*)  d_in[1];
    const int*   pointindex= (const int*)  d_in[2];
    const float* COL       = (const float*)d_in[3];
    const float* OPA       = (const float*)d_in[4];
    const float* p         = (const float*)d_in[5];
    const float* l         = (const float*)d_in[6];
    // d_in[7] = normals (unused), d_in[8] = it (unused)
    const float* hemi      = (const float*)d_in[9];

    float* out = (float*)d_out;
    double* ws = (double*)d_ws;
    unsigned* emptyMask = (unsigned*)((char*)d_ws + EMPTY_OFF);

    prep_points<<<(NPS + 255)/256, 256, 0, stream>>>(p, l, hemi, ws);
    prep_tris<<<(NT + 255)/256, 256, 0, stream>>>(V, ws, emptyMask);
    prep_scatter<<<(NP + 255)/256, 256, 0, stream>>>(indices, pointindex, COL, OPA,
                                                     p, l, emptyMask, out, ws);
    diffuse_main<<<MASKN/256, 256, 0, stream>>>(ws, emptyMask, out);
}

// Round 2
// 107.885 us; speedup vs baseline: 1.3069x; 1.3069x over previous
//
#include <hip/hip_runtime.h>
#include <math.h>

#define NP   512
#define NT   1024
#define NS   25
#define NPS  (NP*NS)            // 12800
#define MASKN (NP*NT*NS)        // 13107200

// ws layout (in doubles):
//  [0,NPS)        dsx
//  [NPS,2NPS)     dsy
//  [2NPS,3NPS)    dsz
//  [3NPS, +3*NP)  pd  (AoS [NP][3])
//  TB = 3*NPS+3*NP: 15 SoA arrays of NT doubles:
//   0:nx 1:ny 2:nz 3:kk 4:a0 5:a1 6:a2 7:b0 8:Bc 9:Dc 10:G2 11:gden 12:gq 13:dc0 14:aq
//  emptyMask: 512 uint32 at byte offset (TB+15*NT)*8
#define TB        (3*NPS + 3*NP)
#define EMPTY_OFF ((size_t)(TB + 15*NT) * 8)

__global__ void prep_points(const float* __restrict__ p,
                            const float* __restrict__ l,
                            const float* __restrict__ hemi,
                            double* __restrict__ ws) {
    int idx = blockIdx.x * 256 + threadIdx.x;
    if (idx >= NPS) return;
    int pi = idx / NS, si = idx % NS;
    double px = p[pi*3+0], py = p[pi*3+1], pz = p[pi*3+2];
    double lx = l[0], ly = l[1], lz = l[2];
    double ux = lx - px, uy = ly - py, uz = lz - pz;
    double nrm = sqrt(ux*ux + uy*uy + uz*uz);
    ux /= nrm; uy /= nrm; uz /= nrm;
    double c = -uy;                    // dot((0,-1,0), u_hat)
    double wx = -uz, wy = 0.0, wz = ux; // cross((0,-1,0), u_hat)
    double m00 = 0.0, m01 = -wz, m02 =  wy;
    double m10 =  wz, m11 = 0.0, m12 = -wx;
    double m20 = -wy, m21 =  wx, m22 = 0.0;
    double q00 = m00*m00 + m01*m10 + m02*m20;
    double q01 = m00*m01 + m01*m11 + m02*m21;
    double q02 = m00*m02 + m01*m12 + m02*m22;
    double q10 = m10*m00 + m11*m10 + m12*m20;
    double q11 = m10*m01 + m11*m11 + m12*m21;
    double q12 = m10*m02 + m11*m12 + m12*m22;
    double q20 = m20*m00 + m21*m10 + m22*m20;
    double q21 = m20*m01 + m21*m11 + m22*m21;
    double q22 = m20*m02 + m21*m12 + m22*m22;
    double ic = 1.0 + c;
    double r00 = 1.0 + m00 + q00/ic, r01 = m01 + q01/ic, r02 = m02 + q02/ic;
    double r10 = m10 + q10/ic, r11 = 1.0 + m11 + q11/ic, r12 = m12 + q12/ic;
    double r20 = m20 + q20/ic, r21 = m21 + q21/ic, r22 = 1.0 + m22 + q22/ic;
    double hx = hemi[si*3+0], hy = hemi[si*3+1], hz = hemi[si*3+2];
    double lhx = r00*hx + r01*hy + r02*hz + lx;
    double lhy = r10*hx + r11*hy + r12*hz + ly;
    double lhz = r20*hx + r21*hy + r22*hz + lz;
    ws[idx]         = lhx - px;   // dsx
    ws[NPS + idx]   = lhy - py;   // dsy
    ws[2*NPS + idx] = lhz - pz;   // dsz
}

__global__ void prep_tris(const float* __restrict__ V,
                          double* __restrict__ ws,
                          unsigned* __restrict__ emptyMask) {
    int n = blockIdx.x * 256 + threadIdx.x;
    if (n < NP) emptyMask[n] = 0u;
    if (n >= NT) return;
    const float* v = V + n*12;
    double v0x=v[0], v0y=v[1], v0z=v[2];
    double v1x=v[3], v1y=v[4], v1z=v[5];
    double v2x=v[6], v2y=v[7], v2z=v[8];
    double v3x=v[9], v3y=v[10], v3z=v[11];
    double e1x=v1x-v0x, e1y=v1y-v0y, e1z=v1z-v0z;
    double e2x=v2x-v0x, e2y=v2y-v0y, e2z=v2z-v0z;
    double cx = e1y*e2z - e1z*e2y;
    double cy = e1z*e2x - e1x*e2z;
    double cz = e1x*e2y - e1y*e2x;
    double nn = sqrt(cx*cx + cy*cy + cz*cz);
    double nx = cx/nn, ny = cy/nn, nz = cz/nn;
    double kk = -(nx*v3x + ny*v3y + nz*v3z);
    double a0=v0x, a1=v0y, a2=v0z;
    double b0=v1x, b1=v1y, b2=v1z;
    double c0=v2x, c1=v2y, c2=v2z;
    double Bc = a0*b2 - a2*b0;
    double Dc = a0*b1 - a1*b0;
    double Ec = a0*c2 - a2*c0;
    double G2 = a1*c0 - a0*c1;
    double Fc = Bc*G2;
    double gden = Dc*(Ec*Dc + Fc);   // gamma denominator (full)
    double gq   = Dc*gden;           // beta/alpha combined denominator core
    double dc0  = Dc*c0;
    double aq   = a0*gq;
    double* T = ws + TB;
    T[0*NT+n]=nx;   T[1*NT+n]=ny;   T[2*NT+n]=nz;   T[3*NT+n]=kk;
    T[4*NT+n]=a0;   T[5*NT+n]=a1;   T[6*NT+n]=a2;   T[7*NT+n]=b0;
    T[8*NT+n]=Bc;   T[9*NT+n]=Dc;   T[10*NT+n]=G2;  T[11*NT+n]=gden;
    T[12*NT+n]=gq;  T[13*NT+n]=dc0; T[14*NT+n]=aq;
}

__global__ void prep_scatter(const int* __restrict__ indices,
                             const int* __restrict__ pointindex,
                             const float* __restrict__ COL,
                             const float* __restrict__ OPA,
                             const float* __restrict__ p,
                             const float* __restrict__ l,
                             unsigned* __restrict__ emptyMask,
                             float* __restrict__ out,
                             double* __restrict__ ws) {
    int i = blockIdx.x * 256 + threadIdx.x;
    if (i >= NP) return;
    int pidx = pointindex[i];
    int local = pidx & (NP - 1);
    int surf = indices[pidx*2 + 0];       // in [0,8)
    int mat  = indices[pidx*2 + 1];
    atomicOr(&emptyMask[local], 1u << surf);
    float* colOut = out + MASKN;
    float* opaOut = out + MASKN + 3*NP;
    float* refOut = out + MASKN + 4*NP;
    colOut[i*3+0] = COL[(surf*8+mat)*3+0];
    colOut[i*3+1] = COL[(surf*8+mat)*3+1];
    colOut[i*3+2] = COL[(surf*8+mat)*3+2];
    float o = OPA[surf*8+mat];
    opaOut[i] = fminf(fmaxf(o, 0.0f), 1.0f);
    refOut[i*3+0] = (float)((double)l[0] - (double)p[i*3+0]);
    refOut[i*3+1] = (float)((double)l[1] - (double)p[i*3+1]);
    refOut[i*3+2] = (float)((double)l[2] - (double)p[i*3+2]);
    double* pd = ws + 3*NPS;
    pd[i*3+0] = (double)p[i*3+0];
    pd[i*3+1] = (double)p[i*3+1];
    pd[i*3+2] = (double)p[i*3+2];
}

// Division-free: output needs only sign(gamma), sign(beta), sign(alpha) and two
// range tests on t = nt/vd. Everything multiplied through by sign-tracked
// denominators; f64 product sign == exact sign, so this matches the np f64
// reference except within ~1e-16 relative of each decision boundary.
__global__ __launch_bounds__(256) void diffuse_main(
        const double* __restrict__ ws,
        const unsigned* __restrict__ emptyMask,
        float* __restrict__ out) {
    const unsigned base = blockIdx.x * 512u;       // 2 elems/thread
    // block-uniform (25600 % 512 == 0, and 512-blocks never straddle a 1024 line)
    const unsigned pp = base / 25600u;
    const unsigned ps = base >> 10;
    const unsigned pi = ps / 25u;

    const double* dsx = ws;
    const double* dsy = ws + NPS;
    const double* dsz = ws + 2*NPS;
    const double* pd  = ws + 3*NPS;
    const double* T   = ws + TB;
    const double* nx = T;          const double* ny = T + NT;
    const double* nz = T + 2*NT;   const double* kk = T + 3*NT;
    const double* a0 = T + 4*NT;   const double* a1 = T + 5*NT;
    const double* a2 = T + 6*NT;   const double* b0 = T + 7*NT;
    const double* Bc = T + 8*NT;   const double* Dc = T + 9*NT;
    const double* G2 = T + 10*NT;  const double* gd = T + 11*NT;
    const double* gq = T + 12*NT;  const double* dq = T + 13*NT;
    const double* aq = T + 14*NT;

    const double sx = dsx[ps], sy = dsy[ps], sz = dsz[ps];
    const double pxi = pd[pi*3+0], pyi = pd[pi*3+1], pzi = pd[pi*3+2];
    const double ox = pd[pp*3+0], oy = pd[pp*3+1], oz = pd[pp*3+2];
    const unsigned em = emptyMask[pp];

    const unsigned f0 = base + threadIdx.x * 2u;
    const unsigned n0 = f0 & 1023u;                 // even -> 16B aligned
    const double2 nx2 = *(const double2*)(nx + n0);
    const double2 ny2 = *(const double2*)(ny + n0);
    const double2 nz2 = *(const double2*)(nz + n0);
    const double2 kk2 = *(const double2*)(kk + n0);
    const unsigned rem0 = f0 - pp * 25600u;

    float res[2];
    #pragma unroll
    for (int k = 0; k < 2; ++k) {
        const double nxv = k ? nx2.y : nx2.x;
        const double nyv = k ? ny2.y : ny2.x;
        const double nzv = k ? nz2.y : nz2.x;
        const double kkv = k ? kk2.y : kk2.x;
        const double vo = fma(pzi, nzv, fma(pyi, nyv, pxi * nxv));
        const double vd = fma(sz, nzv, fma(sy, nyv, sx * nxv));
        const double nt = -(kkv + vo);              // t = nt / vd

        const unsigned rem = rem0 + (unsigned)k;
        const unsigned nn = rem / 25u;
        const unsigned ss = rem - nn * 25u;
        const bool empty = (nn < 8u) && ((em >> nn) & 1u);
        const double e1 = fma(1e-4, vd, nt);        // t > -1e-4  <=>  e1*vd > 0
        const double e2 = vd - nt;                  // t < 1      <=>  e2*vd > 0
        const bool viable = (e1 * vd > 0.0) && (e2 * vd > 0.0) && !empty;

        const unsigned ps2 = pp * 25u + ss;
        const double dx2 = dsx[ps2], dy2 = dsy[ps2], dz2 = dsz[ps2];
        const double R0 = fma(nt, dx2, ox * vd);    // = vd * r0
        const double R1 = fma(nt, dy2, oy * vd);
        const double R2 = fma(nt, dz2, oz * vd);

        const double a0v = a0[nn], a1v = a1[nn], a2v = a2[nn];
        const double Ap = fma(a0v, R2, -(a2v * R0));        // = vd * A
        const double Cp = fma(a0v, R1, -(a1v * R0));        // = vd * C
        const double Dv = Dc[nn], Bv = Bc[nn];
        const double Ng = Dv * fma(Ap, Dv, -(Bv * Cp));     // = vd * gam_num
        const double gdv = gd[nn];
        const double bn = fma(Cp, gdv, Ng * G2[nn]);        // = vd*gden*D*beta
        const double gqv = gq[nn];
        double an = fma(R0, gqv, -(bn * b0[nn]));
        an = fma(-Ng, dq[nn], an);                          // = vd*gden*D*a0*alpha

        const bool ok = viable
            && ((Ng * gdv) * vd > 0.0)      // gam  > 0
            && ((bn * gqv) * vd > 0.0)      // beta > 0
            && ((an * aq[nn]) * vd > 0.0);  // alpha> 0
        res[k] = ok ? 1.0f : 0.0f;
    }
    *(float2*)(out + f0) = make_float2(res[0], res[1]);
}

extern "C" void kernel_launch(void* const* d_in, const int* in_sizes, int n_in,
                              void* d_out, int out_size, void* d_ws, size_t ws_size,
                              hipStream_t stream) {
    const float* V         = (const float*)d_in[0];
    const int*   indices   = (const int*)  d_in[1];
    const int*   pointindex= (const int*)  d_in[2];
    const float* COL       = (const float*)d_in[3];
    const float* OPA       = (const float*)d_in[4];
    const float* p         = (const float*)d_in[5];
    const float* l         = (const float*)d_in[6];
    // d_in[7] = normals (unused), d_in[8] = it (unused)
    const float* hemi      = (const float*)d_in[9];

    float* out = (float*)d_out;
    double* ws = (double*)d_ws;
    unsigned* emptyMask = (unsigned*)((char*)d_ws + EMPTY_OFF);

    prep_points<<<(NPS + 255)/256, 256, 0, stream>>>(p, l, hemi, ws);
    prep_tris<<<(NT + 255)/256, 256, 0, stream>>>(V, ws, emptyMask);
    prep_scatter<<<(NP + 255)/256, 256, 0, stream>>>(indices, pointindex, COL, OPA,
                                                     p, l, emptyMask, out, ws);
    diffuse_main<<<MASKN/512, 256, 0, stream>>>(ws, emptyMask, out);
}

// Round 3
// 41.125 us; speedup vs baseline: 3.4285x; 2.6233x over previous
//
#include <hip/hip_runtime.h>
#include <math.h>

#define NP   512
#define NT   1024
#define NS   25
#define NPS  (NP*NS)            // 12800
#define MASKN (NP*NT*NS)        // 13107200

// ws layout (in doubles):
//  dsA  [NPS][4]   @ 0        (ray d-vectors, AoS, pad to 4)
//  pd   [NP][4]    @ 51200    (points f64)
//  nx   [NT]       @ 53248
//  ny   [NT]       @ 54272
//  nz   [NT]       @ 55296
//  kk   [NT]       @ 56320
//  Wtab [NT][10]   @ 57344    (WG0..2, WB0..2, WA0..2, pad; sign-folded)
//  emptyMask u32[NP] at byte offset 67584*8
#define DSA_OFF  0
#define PD_OFF   51200
#define NX_OFF   53248
#define NY_OFF   54272
#define NZ_OFF   55296
#define KK_OFF   56320
#define W_OFF    57344
#define EMPTY_OFF ((size_t)67584 * 8)

__global__ void prep_points(const float* __restrict__ p,
                            const float* __restrict__ l,
                            const float* __restrict__ hemi,
                            double* __restrict__ ws) {
    int idx = blockIdx.x * 256 + threadIdx.x;
    if (idx >= NPS) return;
    int pi = idx / NS, si = idx % NS;
    double px = p[pi*3+0], py = p[pi*3+1], pz = p[pi*3+2];
    double lx = l[0], ly = l[1], lz = l[2];
    double ux = lx - px, uy = ly - py, uz = lz - pz;
    double nrm = sqrt(ux*ux + uy*uy + uz*uz);
    ux /= nrm; uy /= nrm; uz /= nrm;
    double c = -uy;
    double wx = -uz, wz = ux;          // w = cross((0,-1,0), u_hat), wy = 0
    double m01 = -wz, m02 = 0.0;
    double m10 =  wz, m12 = -wx;
    double m21 =  wx, m20 = 0.0;
    // Q = M*M with wy=0
    double q00 = m01*m10;
    double q01 = 0.0, q10 = 0.0;
    double q02 = m01*m12;
    double q11 = m10*m01 + m12*m21;
    double q12 = 0.0, q21 = 0.0;
    double q20 = m21*m10;
    double q22 = m21*m12;
    double ic = 1.0 + c;
    double r00 = 1.0 + q00/ic, r01 = m01 + q01/ic, r02 = m02 + q02/ic;
    double r10 = m10 + q10/ic, r11 = 1.0 + q11/ic, r12 = m12 + q12/ic;
    double r20 = m20 + q20/ic, r21 = m21 + q21/ic, r22 = 1.0 + q22/ic;
    double hx = hemi[si*3+0], hy = hemi[si*3+1], hz = hemi[si*3+2];
    double lhx = r00*hx + r01*hy + r02*hz + lx;
    double lhy = r10*hx + r11*hy + r12*hz + ly;
    double lhz = r20*hx + r21*hy + r22*hz + lz;
    double* dsA = ws + DSA_OFF;
    dsA[idx*4+0] = lhx - px;
    dsA[idx*4+1] = lhy - py;
    dsA[idx*4+2] = lhz - pz;
    dsA[idx*4+3] = 0.0;
}

__device__ __forceinline__ double sgn(double x) {
    return (x > 0.0) ? 1.0 : ((x < 0.0) ? -1.0 : 0.0);
}

__global__ void prep_tris(const float* __restrict__ V,
                          double* __restrict__ ws,
                          unsigned* __restrict__ emptyMask) {
    int n = blockIdx.x * 256 + threadIdx.x;
    if (n < NP) emptyMask[n] = 0u;
    if (n >= NT) return;
    const float* v = V + n*12;
    double a0=v[0], a1=v[1], a2=v[2];
    double b0=v[3], b1=v[4], b2=v[5];
    double c0=v[6], c1=v[7], c2=v[8];
    double v3x=v[9], v3y=v[10], v3z=v[11];
    double e1x=b0-a0, e1y=b1-a1, e1z=b2-a2;
    double e2x=c0-a0, e2y=c1-a1, e2z=c2-a2;
    double cx = e1y*e2z - e1z*e2y;
    double cy = e1z*e2x - e1x*e2z;
    double cz = e1x*e2y - e1y*e2x;
    double nn = sqrt(cx*cx + cy*cy + cz*cz);
    double nx = cx/nn, ny = cy/nn, nz = cz/nn;
    double kk = -(nx*v3x + ny*v3y + nz*v3z);
    double Bv = a0*b2 - a2*b0;
    double Dv = a0*b1 - a1*b0;
    double Ec = a0*c2 - a2*c0;
    double G2 = a1*c0 - a0*c1;
    double Fc = Bv*G2;
    double gd = Dv*(Ec*Dv + Fc);
    double gq = Dv*gd;
    double dq = Dv*c0;
    double aq = a0*gq;
    // linear forms in R: Ng = Dv*dot(R,WGr); bn = dot(R,WBr); an = dot(R,WAr)
    double WGr0 = a1*Bv - a2*Dv, WGr1 = -(a0*Bv), WGr2 = a0*Dv;
    double dg = Dv*G2;
    double WBr0 = -(a1*gd) + dg*WGr0;
    double WBr1 =  a0*gd  + dg*WGr1;
    double WBr2 =            dg*WGr2;
    double dd = Dv*dq;
    double WAr0 = gq - b0*WBr0 - dd*WGr0;
    double WAr1 =    - b0*WBr1 - dd*WGr1;
    double WAr2 =    - b0*WBr2 - dd*WGr2;
    double sg = sgn(Dv*gd), sb = sgn(gq), sa = sgn(aq);
    ws[NX_OFF + n] = nx;
    ws[NY_OFF + n] = ny;
    ws[NZ_OFF + n] = nz;
    ws[KK_OFF + n] = kk;
    double* W = ws + W_OFF + n*10;
    W[0] = WGr0*sg; W[1] = WGr1*sg; W[2] = WGr2*sg;
    W[3] = WBr0*sb; W[4] = WBr1*sb; W[5] = WBr2*sb;
    W[6] = WAr0*sa; W[7] = WAr1*sa; W[8] = WAr2*sa;
    W[9] = 0.0;
}

__global__ void prep_scatter(const int* __restrict__ indices,
                             const int* __restrict__ pointindex,
                             const float* __restrict__ COL,
                             const float* __restrict__ OPA,
                             const float* __restrict__ p,
                             const float* __restrict__ l,
                             unsigned* __restrict__ emptyMask,
                             float* __restrict__ out,
                             double* __restrict__ ws) {
    int i = blockIdx.x * 256 + threadIdx.x;
    if (i >= NP) return;
    int pidx = pointindex[i];
    int local = pidx & (NP - 1);
    int surf = indices[pidx*2 + 0];       // in [0,8)
    int mat  = indices[pidx*2 + 1];
    atomicOr(&emptyMask[local], 1u << surf);
    float* colOut = out + MASKN;
    float* opaOut = out + MASKN + 3*NP;
    float* refOut = out + MASKN + 4*NP;
    colOut[i*3+0] = COL[(surf*8+mat)*3+0];
    colOut[i*3+1] = COL[(surf*8+mat)*3+1];
    colOut[i*3+2] = COL[(surf*8+mat)*3+2];
    float o = OPA[surf*8+mat];
    opaOut[i] = fminf(fmaxf(o, 0.0f), 1.0f);
    refOut[i*3+0] = (float)((double)l[0] - (double)p[i*3+0]);
    refOut[i*3+1] = (float)((double)l[1] - (double)p[i*3+1]);
    refOut[i*3+2] = (float)((double)l[2] - (double)p[i*3+2]);
    double* pd = ws + PD_OFF;
    pd[i*4+0] = (double)p[i*3+0];
    pd[i*4+1] = (double)p[i*3+1];
    pd[i*4+2] = (double)p[i*3+2];
    pd[i*4+3] = 0.0;
}

// One block per 1024-triangle output line: ps = f>>10 = blockIdx.x uniform,
// pp = pi = ps/25 uniform. Per-element: coalesced nrm/kk loads, LDS reads of
// the staged W-slice (42 rows) and 25 ray d-vectors; all sign tests are
// dot(R, W)*vd > 0 with denominator signs folded into W at prep time.
__global__ __launch_bounds__(256) void diffuse_main(
        const double* __restrict__ ws,
        const unsigned* __restrict__ emptyMask,
        float* __restrict__ out) {
    __shared__ double sW[42][10];
    __shared__ double sdx[25], sdy[25], sdz[25];

    const unsigned ps = blockIdx.x;
    const unsigned pp = ps / 25u;
    const unsigned q  = ps - pp * 25u;
    const unsigned nn0 = (q << 10) / 25u;
    const unsigned tid = threadIdx.x;

    const double* Wg = ws + W_OFF;
    // stage W rows nn0..nn0+41 (clamped)
    {
        unsigned i = tid;
        if (i < 210u) {
            unsigned row = i / 5u, col = i - row * 5u;
            unsigned gn = nn0 + row; if (gn > 1023u) gn = 1023u;
            const double2 v = *(const double2*)(Wg + gn*10u + col*2u);
            sW[row][col*2u]   = v.x;
            sW[row][col*2u+1] = v.y;
        }
        if (i < 25u) {
            const double* dr = ws + DSA_OFF + (pp*25u + i)*4u;
            sdx[i] = dr[0]; sdy[i] = dr[1]; sdz[i] = dr[2];
        }
    }
    // block-uniform scalars (broadcast loads)
    const double sx = ws[DSA_OFF + ps*4u + 0];
    const double sy = ws[DSA_OFF + ps*4u + 1];
    const double sz = ws[DSA_OFF + ps*4u + 2];
    const double ox = ws[PD_OFF + pp*4u + 0];
    const double oy = ws[PD_OFF + pp*4u + 1];
    const double oz = ws[PD_OFF + pp*4u + 2];
    const unsigned em = emptyMask[pp];
    __syncthreads();

    const unsigned n0 = tid * 4u;
    const double2 nxa = *(const double2*)(ws + NX_OFF + n0);
    const double2 nxb = *(const double2*)(ws + NX_OFF + n0 + 2);
    const double2 nya = *(const double2*)(ws + NY_OFF + n0);
    const double2 nyb = *(const double2*)(ws + NY_OFF + n0 + 2);
    const double2 nza = *(const double2*)(ws + NZ_OFF + n0);
    const double2 nzb = *(const double2*)(ws + NZ_OFF + n0 + 2);
    const double2 kka = *(const double2*)(ws + KK_OFF + n0);
    const double2 kkb = *(const double2*)(ws + KK_OFF + n0 + 2);
    const unsigned rem0 = (q << 10) + n0;

    float res[4];
    #pragma unroll
    for (int k = 0; k < 4; ++k) {
        const double nxv = (k < 2) ? (k ? nxa.y : nxa.x) : (k == 3 ? nxb.y : nxb.x);
        const double nyv = (k < 2) ? (k ? nya.y : nya.x) : (k == 3 ? nyb.y : nyb.x);
        const double nzv = (k < 2) ? (k ? nza.y : nza.x) : (k == 3 ? nzb.y : nzb.x);
        const double kkv = (k < 2) ? (k ? kka.y : kka.x) : (k == 3 ? kkb.y : kkb.x);

        const double vd = fma(sz, nzv, fma(sy, nyv, sx * nxv));
        const double tt = fma(oz, nzv, fma(oy, nyv, fma(ox, nxv, kkv))); // nt = -tt
        const double e1 = fma(1e-4, vd, -tt);      // t > -1e-4  <=>  e1*vd > 0
        const double e2 = vd + tt;                 // t < 1      <=>  e2*vd > 0

        const unsigned rem = rem0 + (unsigned)k;
        const unsigned nn = rem / 25u;
        const unsigned ss = rem - nn * 25u;
        const bool empty = (nn < 8u) && ((em >> nn) & 1u);

        const double dxv = sdx[ss], dyv = sdy[ss], dzv = sdz[ss];
        const double R0 = fma(-tt, dxv, vd * ox);  // = vd * r0
        const double R1 = fma(-tt, dyv, vd * oy);
        const double R2 = fma(-tt, dzv, vd * oz);

        const double* w = sW[nn - nn0];
        const double dG = fma(R2, w[2], fma(R1, w[1], R0 * w[0]));
        const double dB = fma(R2, w[5], fma(R1, w[4], R0 * w[3]));
        const double dA = fma(R2, w[8], fma(R1, w[7], R0 * w[6]));

        const bool ok = (e1 * vd > 0.0) && (e2 * vd > 0.0) && !empty
                     && (dG * vd > 0.0) && (dB * vd > 0.0) && (dA * vd > 0.0);
        res[k] = ok ? 1.0f : 0.0f;
    }
    *(float4*)(out + ps*1024u + n0) = make_float4(res[0], res[1], res[2], res[3]);
}

extern "C" void kernel_launch(void* const* d_in, const int* in_sizes, int n_in,
                              void* d_out, int out_size, void* d_ws, size_t ws_size,
                              hipStream_t stream) {
    const float* V         = (const float*)d_in[0];
    const int*   indices   = (const int*)  d_in[1];
    const int*   pointindex= (const int*)  d_in[2];
    const float* COL       = (const float*)d_in[3];
    const float* OPA       = (const float*)d_in[4];
    const float* p         = (const float*)d_in[5];
    const float* l         = (const float*)d_in[6];
    // d_in[7] = normals (unused), d_in[8] = it (unused)
    const float* hemi      = (const float*)d_in[9];

    float* out = (float*)d_out;
    double* ws = (double*)d_ws;
    unsigned* emptyMask = (unsigned*)((char*)d_ws + EMPTY_OFF);

    prep_points<<<(NPS + 255)/256, 256, 0, stream>>>(p, l, hemi, ws);
    prep_tris<<<(NT + 255)/256, 256, 0, stream>>>(V, ws, emptyMask);
    prep_scatter<<<(NP + 255)/256, 256, 0, stream>>>(indices, pointindex, COL, OPA,
                                                     p, l, emptyMask, out, ws);
    diffuse_main<<<NPS, 256, 0, stream>>>(ws, emptyMask, out);
}

// Round 4
// 39.905 us; speedup vs baseline: 3.5334x; 1.0306x over previous
//
#include <hip/hip_runtime.h>
#include <math.h>

#define NP   512
#define NT   1024
#define NS   25
#define NPS  (NP*NS)            // 12800
#define MASKN (NP*NT*NS)        // 13107200

// ws layout (in doubles):
//  dsA  [NPS][4]   @ 0        (ray d-vectors, AoS, pad to 4)
//  pd   [NP][4]    @ 51200    (points f64)
//  nx   [NT]       @ 53248
//  ny   [NT]       @ 54272
//  nz   [NT]       @ 55296
//  kk   [NT]       @ 56320
//  Wtab [NT][10]   @ 57344    (WG0..2, WB0..2, WA0..2, pad; sign-folded)
//  emptyMask u32[NP] at byte offset 67584*8
#define DSA_OFF  0
#define PD_OFF   51200
#define NX_OFF   53248
#define NY_OFF   54272
#define NZ_OFF   55296
#define KK_OFF   56320
#define W_OFF    57344
#define EMPTY_OFF ((size_t)67584 * 8)

__device__ __forceinline__ double sgn(double x) {
    return (x > 0.0) ? 1.0 : ((x < 0.0) ? -1.0 : 0.0);
}

// Fused prep: blocks 0..49 rays, 50..53 triangle tables, 54 scatter+emptyMask.
__global__ void prep_all(const float* __restrict__ p,
                         const float* __restrict__ l,
                         const float* __restrict__ hemi,
                         const float* __restrict__ V,
                         const int* __restrict__ indices,
                         const int* __restrict__ pointindex,
                         const float* __restrict__ COL,
                         const float* __restrict__ OPA,
                         double* __restrict__ ws,
                         unsigned* __restrict__ emptyMask,
                         float* __restrict__ out) {
    const int b = blockIdx.x, t = threadIdx.x;
    if (b < 50) {
        // ---- ray d-vectors ----
        int idx = b * 256 + t;                 // < 12800 exactly
        int pi = idx / NS, si = idx % NS;
        double px = p[pi*3+0], py = p[pi*3+1], pz = p[pi*3+2];
        double lx = l[0], ly = l[1], lz = l[2];
        double ux = lx - px, uy = ly - py, uz = lz - pz;
        double nrm = sqrt(ux*ux + uy*uy + uz*uz);
        ux /= nrm; uy /= nrm; uz /= nrm;
        double c = -uy;
        double wx = -uz, wz = ux;              // w = cross((0,-1,0), u_hat), wy=0
        double m01 = -wz, m10 = wz, m12 = -wx, m21 = wx;
        double q00 = m01*m10;
        double q02 = m01*m12;
        double q11 = m10*m01 + m12*m21;
        double q20 = m21*m10;
        double q22 = m21*m12;
        double ic = 1.0 + c;
        double r00 = 1.0 + q00/ic, r01 = m01,            r02 = q02/ic;
        double r10 = m10,          r11 = 1.0 + q11/ic,   r12 = m12;
        double r20 = q20/ic,       r21 = m21,            r22 = 1.0 + q22/ic;
        double hx = hemi[si*3+0], hy = hemi[si*3+1], hz = hemi[si*3+2];
        double lhx = r00*hx + r01*hy + r02*hz + lx;
        double lhy = r10*hx + r11*hy + r12*hz + ly;
        double lhz = r20*hx + r21*hy + r22*hz + lz;
        double* dsA = ws + DSA_OFF;
        dsA[idx*4+0] = lhx - px;
        dsA[idx*4+1] = lhy - py;
        dsA[idx*4+2] = lhz - pz;
        dsA[idx*4+3] = 0.0;
    } else if (b < 54) {
        // ---- per-triangle tables ----
        int n = (b - 50) * 256 + t;            // < 1024 exactly
        const float* v = V + n*12;
        double a0=v[0], a1=v[1], a2=v[2];
        double b0=v[3], b1=v[4], b2=v[5];
        double c0=v[6], c1=v[7], c2=v[8];
        double v3x=v[9], v3y=v[10], v3z=v[11];
        double e1x=b0-a0, e1y=b1-a1, e1z=b2-a2;
        double e2x=c0-a0, e2y=c1-a1, e2z=c2-a2;
        double cx = e1y*e2z - e1z*e2y;
        double cy = e1z*e2x - e1x*e2z;
        double cz = e1x*e2y - e1y*e2x;
        double nn = sqrt(cx*cx + cy*cy + cz*cz);
        double nx = cx/nn, ny = cy/nn, nz = cz/nn;
        double kk = -(nx*v3x + ny*v3y + nz*v3z);
        double Bv = a0*b2 - a2*b0;
        double Dv = a0*b1 - a1*b0;
        double Ec = a0*c2 - a2*c0;
        double G2 = a1*c0 - a0*c1;
        double Fc = Bv*G2;
        double gd = Dv*(Ec*Dv + Fc);
        double gq = Dv*gd;
        double dq = Dv*c0;
        double aq = a0*gq;
        double WGr0 = a1*Bv - a2*Dv, WGr1 = -(a0*Bv), WGr2 = a0*Dv;
        double dg = Dv*G2;
        double WBr0 = -(a1*gd) + dg*WGr0;
        double WBr1 =  a0*gd  + dg*WGr1;
        double WBr2 =            dg*WGr2;
        double dd = Dv*dq;
        double WAr0 = gq - b0*WBr0 - dd*WGr0;
        double WAr1 =    - b0*WBr1 - dd*WGr1;
        double WAr2 =    - b0*WBr2 - dd*WGr2;
        double sg = sgn(Dv*gd), sb = sgn(gq), sa = sgn(aq);
        ws[NX_OFF + n] = nx;
        ws[NY_OFF + n] = ny;
        ws[NZ_OFF + n] = nz;
        ws[KK_OFF + n] = kk;
        double* W = ws + W_OFF + n*10;
        W[0] = WGr0*sg; W[1] = WGr1*sg; W[2] = WGr2*sg;
        W[3] = WBr0*sb; W[4] = WBr1*sb; W[5] = WBr2*sb;
        W[6] = WAr0*sa; W[7] = WAr1*sa; W[8] = WAr2*sa;
        W[9] = 0.0;
    } else {
        // ---- scatter outputs + emptyMask (zero, then atomicOr, one block) ----
        emptyMask[t] = 0u;
        emptyMask[t + 256] = 0u;
        __syncthreads();
        for (int i = t; i < NP; i += 256) {
            int pidx = pointindex[i];
            int local = pidx & (NP - 1);
            int surf = indices[pidx*2 + 0];
            int mat  = indices[pidx*2 + 1];
            atomicOr(&emptyMask[local], 1u << surf);
            float* colOut = out + MASKN;
            float* opaOut = out + MASKN + 3*NP;
            float* refOut = out + MASKN + 4*NP;
            colOut[i*3+0] = COL[(surf*8+mat)*3+0];
            colOut[i*3+1] = COL[(surf*8+mat)*3+1];
            colOut[i*3+2] = COL[(surf*8+mat)*3+2];
            float o = OPA[surf*8+mat];
            opaOut[i] = fminf(fmaxf(o, 0.0f), 1.0f);
            refOut[i*3+0] = (float)((double)l[0] - (double)p[i*3+0]);
            refOut[i*3+1] = (float)((double)l[1] - (double)p[i*3+1]);
            refOut[i*3+2] = (float)((double)l[2] - (double)p[i*3+2]);
            double* pd = ws + PD_OFF;
            pd[i*4+0] = (double)p[i*3+0];
            pd[i*4+1] = (double)p[i*3+1];
            pd[i*4+2] = (double)p[i*3+2];
            pd[i*4+3] = 0.0;
        }
    }
}

// Inner body, templated on whether the empty-mask can apply (only q==0 blocks:
// nn < 8 requires rem < 200, i.e. the first line of each pp group).
template<bool HE>
__device__ __forceinline__ void line_body(
        const double* __restrict__ ws, const double (*sW)[11],
        const double* sdx, const double* sdy, const double* sdz,
        double sx, double sy, double sz, double ox, double oy, double oz,
        unsigned em, unsigned nn0, unsigned q, unsigned ps, unsigned tid,
        float* __restrict__ out) {
    const unsigned n0 = tid * 4u;
    const double2 nxa = *(const double2*)(ws + NX_OFF + n0);
    const double2 nxb = *(const double2*)(ws + NX_OFF + n0 + 2);
    const double2 nya = *(const double2*)(ws + NY_OFF + n0);
    const double2 nyb = *(const double2*)(ws + NY_OFF + n0 + 2);
    const double2 nza = *(const double2*)(ws + NZ_OFF + n0);
    const double2 nzb = *(const double2*)(ws + NZ_OFF + n0 + 2);
    const double2 kka = *(const double2*)(ws + KK_OFF + n0);
    const double2 kkb = *(const double2*)(ws + KK_OFF + n0 + 2);

    const unsigned rem0 = (q << 10) + n0;
    unsigned nn = rem0 / 25u;               // one divide per thread
    unsigned ss = rem0 - nn * 25u;

    float res[4];
    #pragma unroll
    for (int k = 0; k < 4; ++k) {
        const double nxv = (k < 2) ? (k ? nxa.y : nxa.x) : (k == 3 ? nxb.y : nxb.x);
        const double nyv = (k < 2) ? (k ? nya.y : nya.x) : (k == 3 ? nyb.y : nyb.x);
        const double nzv = (k < 2) ? (k ? nza.y : nza.x) : (k == 3 ? nzb.y : nzb.x);
        const double kkv = (k < 2) ? (k ? kka.y : kka.x) : (k == 3 ? kkb.y : kkb.x);

        const double vd = fma(sz, nzv, fma(sy, nyv, sx * nxv));
        const double tt = fma(oz, nzv, fma(oy, nyv, fma(ox, nxv, kkv))); // nt=-tt
        const double e1 = fma(1e-4, vd, -tt);   // t > -1e-4 <=> sign(e1)==sign(vd)
        const double e2 = vd + tt;              // t < 1     <=> sign(e2)==sign(vd)

        const double dxv = sdx[ss], dyv = sdy[ss], dzv = sdz[ss];
        const double R0 = fma(-tt, dxv, vd * ox);   // = vd * r0
        const double R1 = fma(-tt, dyv, vd * oy);
        const double R2 = fma(-tt, dzv, vd * oz);

        const double* w = sW[nn - nn0];
        const double dG = fma(R2, w[2], fma(R1, w[1], R0 * w[0]));
        const double dB = fma(R2, w[5], fma(R1, w[4], R0 * w[3]));
        const double dA = fma(R2, w[8], fma(R1, w[7], R0 * w[6]));

        // sign(x*vd) > 0 for all five <=> hi-bit of OR of sign xors is clear
        const int hv = __double2hiint(vd);
        int m = (__double2hiint(e1) ^ hv) | (__double2hiint(e2) ^ hv)
              | (__double2hiint(dG) ^ hv) | (__double2hiint(dB) ^ hv)
              | (__double2hiint(dA) ^ hv);
        bool ok = (m >= 0);
        if (HE) ok = ok && !((nn < 8u) && ((em >> nn) & 1u));
        res[k] = ok ? 1.0f : 0.0f;

        ++ss;
        if (ss == 25u) { ss = 0u; ++nn; }
    }
    *(float4*)(out + ps*1024u + n0) = make_float4(res[0], res[1], res[2], res[3]);
}

__global__ __launch_bounds__(256) void diffuse_main(
        const double* __restrict__ ws,
        const unsigned* __restrict__ emptyMask,
        float* __restrict__ out) {
    __shared__ double sW[42][11];          // stride 11: 22-bank step, no row alias
    __shared__ double sdx[25], sdy[25], sdz[25];

    const unsigned ps = blockIdx.x;
    const unsigned pp = ps / 25u;
    const unsigned q  = ps - pp * 25u;
    const unsigned nn0 = (q << 10) / 25u;
    const unsigned tid = threadIdx.x;

    const double* Wg = ws + W_OFF;
    {
        unsigned i = tid;
        if (i < 210u) {
            unsigned row = i / 5u, col = i - row * 5u;
            unsigned gn = nn0 + row; if (gn > 1023u) gn = 1023u;
            const double2 v = *(const double2*)(Wg + gn*10u + col*2u);
            sW[row][col*2u]   = v.x;
            sW[row][col*2u+1] = v.y;
        }
        if (i < 25u) {
            const double* dr = ws + DSA_OFF + (pp*25u + i)*4u;
            sdx[i] = dr[0]; sdy[i] = dr[1]; sdz[i] = dr[2];
        }
    }
    const double sx = ws[DSA_OFF + ps*4u + 0];
    const double sy = ws[DSA_OFF + ps*4u + 1];
    const double sz = ws[DSA_OFF + ps*4u + 2];
    const double ox = ws[PD_OFF + pp*4u + 0];
    const double oy = ws[PD_OFF + pp*4u + 1];
    const double oz = ws[PD_OFF + pp*4u + 2];
    const unsigned em = (q == 0u) ? emptyMask[pp] : 0u;
    __syncthreads();

    if (q == 0u)
        line_body<true >(ws, sW, sdx, sdy, sdz, sx, sy, sz, ox, oy, oz,
                         em, nn0, q, ps, tid, out);
    else
        line_body<false>(ws, sW, sdx, sdy, sdz, sx, sy, sz, ox, oy, oz,
                         em, nn0, q, ps, tid, out);
}

extern "C" void kernel_launch(void* const* d_in, const int* in_sizes, int n_in,
                              void* d_out, int out_size, void* d_ws, size_t ws_size,
                              hipStream_t stream) {
    const float* V         = (const float*)d_in[0];
    const int*   indices   = (const int*)  d_in[1];
    const int*   pointindex= (const int*)  d_in[2];
    const float* COL       = (const float*)d_in[3];
    const float* OPA       = (const float*)d_in[4];
    const float* p         = (const float*)d_in[5];
    const float* l         = (const float*)d_in[6];
    // d_in[7] = normals (unused), d_in[8] = it (unused)
    const float* hemi      = (const float*)d_in[9];

    float* out = (float*)d_out;
    double* ws = (double*)d_ws;
    unsigned* emptyMask = (unsigned*)((char*)d_ws + EMPTY_OFF);

    prep_all<<<55, 256, 0, stream>>>(p, l, hemi, V, indices, pointindex,
                                     COL, OPA, ws, emptyMask, out);
    diffuse_main<<<NPS, 256, 0, stream>>>(ws, emptyMask, out);
}